// Round 6
// baseline (296.679 us; speedup 1.0000x reference)
//
#include <hip/hip_runtime.h>
#include <math.h>

#define NB 8
#define NA 512
#define NN 64
#define ND 128
#define NF 128
#define NG 25
#define NGA 512

typedef __attribute__((ext_vector_type(8))) short bf16x8;
typedef __attribute__((ext_vector_type(4))) float f32x4;

__device__ __forceinline__ float sspf(float v) {
  return fmaxf(v, 0.0f) + __logf(1.0f + __expf(-fabsf(v))) - 0.6931471805599453f;
}

__device__ __forceinline__ short f2bf(float x) {
  union { float f; unsigned u; } v; v.f = x;
  unsigned r = v.u + 0x7fffu + ((v.u >> 16) & 1u);   // RNE
  return (short)(r >> 16);
}

__device__ __forceinline__ unsigned pk2bf(float a, float b) {
  union { float f; unsigned u; } x, y; x.f = a; y.f = b;
  const unsigned ra = (x.u + 0x7fffu + ((x.u >> 16) & 1u)) >> 16;
  const unsigned rb = (y.u + 0x7fffu + ((y.u >> 16) & 1u)) & 0xffff0000u;
  return ra | rb;
}

__device__ __forceinline__ float bf2f(unsigned short us) {
  union { unsigned u; float f; } v; v.u = ((unsigned)us) << 16; return v.f;
}

__device__ __forceinline__ bf16x8 pack8(float4 a, float4 b) {
  bf16x8 r;
  r[0] = f2bf(a.x); r[1] = f2bf(a.y); r[2] = f2bf(a.z); r[3] = f2bf(a.w);
  r[4] = f2bf(b.x); r[5] = f2bf(b.y); r[6] = f2bf(b.z); r[7] = f2bf(b.w);
  return r;
}

// ---------------- prep: bf16 transposed weight copies ----------------
#define NW1 (3 * 128 * 32)       // 12288
#define NSQ (3 * 128 * 128)     // 49152
#define NAW (3 * 128 * 512)     // 196608
__global__ __launch_bounds__(256) void k_prepw(
    const float* __restrict__ fw1, const float* __restrict__ fw2,
    const float* __restrict__ in2f, const float* __restrict__ aw,
    short* __restrict__ w1T, short* __restrict__ w2T,
    short* __restrict__ in2fT, short* __restrict__ awT) {
  int idx = blockIdx.x * 256 + threadIdx.x;
  if (idx < NW1) {
    const int l = idx >> 12, r = idx & 4095, n = r >> 5, k = r & 31;
    w1T[idx] = (k < NG) ? f2bf(fw1[(size_t)l * NG * NF + k * NF + n]) : (short)0;
    return;
  }
  idx -= NW1;
  if (idx < 2 * NSQ) {
    const int which = idx / NSQ, q = idx % NSQ;
    const int l = q >> 14, r = q & 16383, n = r >> 7, k = r & 127;
    const float* src = (which == 0) ? fw2 : in2f;
    short* dst = (which == 0) ? w2T : in2fT;
    dst[q] = f2bf(src[(size_t)l * 16384 + k * 128 + n]);
    return;
  }
  idx -= 2 * NSQ;
  if (idx < NAW) {
    const int l = idx >> 16, r = idx & 65535, n = r >> 9, k = r & 511;
    awT[idx] = f2bf(aw[(size_t)l * 65536 + k * 128 + n]);
  }
}

// ---------------- fused weight: W12 = f2o@dw, b12 = f2ob@dw + db ----------------
// grid (8 itiles, 3 layers), 256 thr. Output W12T[l][j][i] bf16, b12[l][j] fp32.
__global__ __launch_bounds__(256) void k_prepfuse(
    const float* __restrict__ f2o, const float* __restrict__ f2ob,
    const float* __restrict__ dw, const float* __restrict__ db,
    short* __restrict__ W12T, float* __restrict__ b12) {
  const int t = threadIdx.x;
  const int lane = t & 63, wave = t >> 6;
  const int lanelo = lane & 15, quad = lane >> 4;
  const int wbase = wave << 5;
  const int l = blockIdx.y;
  const int i = (blockIdx.x << 4) + lanelo;
  const float* f2o_l = f2o + (size_t)l * 16384;
  const float* dw_l = dw + (size_t)l * 16384;
  short* W12T_l = W12T + (size_t)l * 16384;

  f32x4 c[2] = {{0.f, 0.f, 0.f, 0.f}, {0.f, 0.f, 0.f, 0.f}};
#pragma unroll
  for (int kt = 0; kt < 4; ++kt) {
    const int k0 = kt * 32 + quad * 8;
    const bf16x8 b = pack8(*(const float4*)(f2o_l + (size_t)i * 128 + k0),
                           *(const float4*)(f2o_l + (size_t)i * 128 + k0 + 4));
#pragma unroll
    for (int ct = 0; ct < 2; ++ct) {
      const int j = wbase + ct * 16 + lanelo;
      bf16x8 a;
#pragma unroll
      for (int idx = 0; idx < 8; ++idx)
        a[idx] = f2bf(dw_l[(size_t)(k0 + idx) * 128 + j]);
      c[ct] = __builtin_amdgcn_mfma_f32_16x16x32_bf16(a, b, c[ct], 0, 0, 0);
    }
  }
#pragma unroll
  for (int ct = 0; ct < 2; ++ct) {
#pragma unroll
    for (int reg = 0; reg < 4; ++reg) {
      const int j = wbase + ct * 16 + quad * 4 + reg;
      W12T_l[(size_t)j * 128 + i] = f2bf(c[ct][reg]);
    }
  }
  if (blockIdx.x == 0 && t < 128) {
    const int j = t;
    float acc = db[(size_t)l * 128 + j];
    for (int k = 0; k < 128; ++k)
      acc += f2ob[(size_t)l * 128 + k] * dw_l[(size_t)k * 128 + j];
    b12[(size_t)l * 128 + j] = acc;
  }
}

// ---------------- embY = emb @ in2f[0] -> bf16 [112][128] (rows >=100 skipped) ----
__global__ __launch_bounds__(256) void k_prepemb(const float* __restrict__ emb,
                                                 const short* __restrict__ in2fT0,
                                                 short* __restrict__ embYB) {
  const int t = threadIdx.x;
  const int lane = t & 63, wave = t >> 6;
  const int lanelo = lane & 15, quad = lane >> 4;
  const int wbase = wave << 5;
  const int z = (blockIdx.x << 4) + lanelo;
  const int zc = (z < 100) ? z : 99;
  f32x4 c[2] = {{0.f, 0.f, 0.f, 0.f}, {0.f, 0.f, 0.f, 0.f}};
#pragma unroll
  for (int kt = 0; kt < 4; ++kt) {
    const int k0 = kt * 32 + quad * 8;
    const bf16x8 b = pack8(*(const float4*)(emb + (size_t)zc * 128 + k0),
                           *(const float4*)(emb + (size_t)zc * 128 + k0 + 4));
#pragma unroll
    for (int ct = 0; ct < 2; ++ct) {
      const bf16x8 a = *(const bf16x8*)(in2fT0 + (wbase + ct * 16 + lanelo) * 128 + k0);
      c[ct] = __builtin_amdgcn_mfma_f32_16x16x32_bf16(a, b, c[ct], 0, 0, 0);
    }
  }
  if (z < 100) {
#pragma unroll
    for (int ct = 0; ct < 2; ++ct) {
      const int c0 = wbase + ct * 16 + quad * 4;
      uint2 pk; pk.x = pk2bf(c[ct][0], c[ct][1]); pk.y = pk2bf(c[ct][2], c[ct][3]);
      *(uint2*)(embYB + (size_t)z * 128 + c0) = pk;
    }
  }
}

// ---------------- gather: x = emb[zn], yB = embYB[zn] ----------------
__global__ __launch_bounds__(256) void k_init2(const int* __restrict__ zn,
                                               const float* __restrict__ emb,
                                               const short* __restrict__ embYB,
                                               float* __restrict__ x,
                                               short* __restrict__ yB) {
  const int t = threadIdx.x;
  const int ga = blockIdx.x * 2 + (t >> 7);
  const int tt = t & 127;
  const int z = zn[ga];
  x[(size_t)ga * 128 + tt] = emb[(size_t)z * 128 + tt];
  yB[(size_t)ga * 128 + tt] = embYB[(size_t)z * 128 + tt];
}

// ---------------- hoisted angular GEMM: vang[l] = bf16(Gi) @ awT[l] ----------------
__global__ __launch_bounds__(256) void k_vang(const float* __restrict__ Gi,
                                              const short* __restrict__ awT,
                                              float* __restrict__ vang) {
  const int t = threadIdx.x;
  const int lane = t & 63, wave = t >> 6;
  const int lanelo = lane & 15, quad = lane >> 4;
  const int wbase = wave << 5;
  const int l = blockIdx.y;
  const int row = (blockIdx.x << 4) + lanelo;
  const short* aw = awT + (size_t)l * 128 * NGA;
  f32x4 c[2] = {{0.f, 0.f, 0.f, 0.f}, {0.f, 0.f, 0.f, 0.f}};
#pragma unroll
  for (int kt = 0; kt < 16; ++kt) {
    const int k0 = kt * 32 + quad * 8;
    const bf16x8 b = pack8(*(const float4*)(Gi + (size_t)row * NGA + k0),
                           *(const float4*)(Gi + (size_t)row * NGA + k0 + 4));
#pragma unroll
    for (int ct = 0; ct < 2; ++ct) {
      const bf16x8 a = *(const bf16x8*)(aw + (size_t)(wbase + ct * 16 + lanelo) * NGA + k0);
      c[ct] = __builtin_amdgcn_mfma_f32_16x16x32_bf16(a, b, c[ct], 0, 0, 0);
    }
  }
  float* vrow = vang + ((size_t)l * NB * NA + row) * 128;
#pragma unroll
  for (int ct = 0; ct < 2; ++ct) {
    float4 o = make_float4(c[ct][0], c[ct][1], c[ct][2], c[ct][3]);
    *(float4*)(vrow + wbase + ct * 16 + quad * 4) = o;
  }
}

// ---------------- fused CFConv (y prefetched to LDS as bf16) ----------------
#define HPAD 136
#define SYPAD 136
__global__ __launch_bounds__(128) void k_cfconv(
    const float* __restrict__ pos, const int* __restrict__ nbr,
    const int* __restrict__ nmask, const short* __restrict__ yB,
    const short* __restrict__ w1T, const float* __restrict__ b1,
    const short* __restrict__ w2T, const float* __restrict__ b2,
    short* __restrict__ aggB) {
  __shared__ alignas(16) short sH[NN * HPAD];     // aliased as sPart at end
  __shared__ alignas(16) short sYB[NN * SYPAD];   // neighbor y rows, bf16
  __shared__ float sR[NN];
  __shared__ float sScale[NN];
  __shared__ int sNbr[NN];

  const int t = threadIdx.x;
  const int ga = blockIdx.x;
  const int b0 = ga & ~(NA - 1);
  const int lane = t & 63;
  const int wave = t >> 6;
  const int lanelo = lane & 15;
  const int quad = lane >> 4;
  const int wbase = wave << 6;

  // weight B-frags (broadcast across blocks -> L2)
  bf16x8 bw1[4];
  bf16x8 bw2[16];
#pragma unroll
  for (int ct = 0; ct < 4; ++ct) {
    const int n = wbase + ct * 16 + lanelo;
    bw1[ct] = *(const bf16x8*)(w1T + n * 32 + quad * 8);
#pragma unroll
    for (int kt = 0; kt < 4; ++kt)
      bw2[ct * 4 + kt] = *(const bf16x8*)(w2T + n * 128 + kt * 32 + quad * 8);
  }
  float b1r[4], b2r[4];
#pragma unroll
  for (int ct = 0; ct < 4; ++ct) {
    b1r[ct] = b1[wbase + ct * 16 + lanelo];
    b2r[ct] = b2[wbase + ct * 16 + lanelo];
  }

  if (t < NN) {
    const int nj = nbr[(size_t)ga * NN + t];
    sNbr[t] = nj;
    const float px = pos[(size_t)ga * 3];
    const float py = pos[(size_t)ga * 3 + 1];
    const float pz = pos[(size_t)ga * 3 + 2];
    const float* pj = pos + (size_t)(b0 + nj) * 3;
    const float dx = pj[0] - px, dy = pj[1] - py, dz = pj[2] - pz;
    const float r = sqrtf(dx * dx + dy * dy + dz * dz + 1e-12f);
    sR[t] = r;
    sScale[t] = (r <= 5.0f && nmask[(size_t)ga * NN + t] != 0) ? 1.0f : 0.0f;
  }
  __syncthreads();

  // ---- prefetch neighbor y rows (coalesced 16B loads), park in regs ----
  const int jrow = t >> 4;          // 0..7
  const int fc = (t & 15) * 8;      // 8 bf16 = 16 B per thread
  uint4 yreg[8];
#pragma unroll
  for (int i = 0; i < 8; ++i) {
    const int j = i * 8 + jrow;
    yreg[i] = *(const uint4*)(yB + (size_t)(b0 + sNbr[j]) * NF + fc);
  }

  const float step = 3.8f / 24.0f;
  const float coef = -0.5f / (step * step);

  // ---- phase 1: h = ssp(f @ w1 + b1) -> bf16 LDS (overlaps y loads) ----
#pragma unroll
  for (int rt = 0; rt < 4; ++rt) {
    const float r = sR[rt * 16 + lanelo];
    bf16x8 a;
#pragma unroll
    for (int i = 0; i < 8; ++i) {
      const int g = quad * 8 + i;
      const float d = r - (1.2f + step * (float)g);
      const float e = __expf(coef * d * d);
      a[i] = (g < NG) ? f2bf(e) : (short)0;
    }
#pragma unroll
    for (int ct = 0; ct < 4; ++ct) {
      f32x4 c = {0.f, 0.f, 0.f, 0.f};
      c = __builtin_amdgcn_mfma_f32_16x16x32_bf16(a, bw1[ct], c, 0, 0, 0);
      const int f = wbase + ct * 16 + lanelo;
      const float b1f = b1r[ct];
#pragma unroll
      for (int reg = 0; reg < 4; ++reg) {
        const int j = rt * 16 + quad * 4 + reg;
        sH[j * HPAD + f] = f2bf(sspf(c[reg] + b1f));
      }
    }
  }
  // stash prefetched y rows into LDS
#pragma unroll
  for (int i = 0; i < 8; ++i) {
    const int j = i * 8 + jrow;
    *(uint4*)(sYB + j * SYPAD + fc) = yreg[i];
  }
  __syncthreads();

  // ---- phase 2: W = h @ w2; consume against LDS y ----
  float pagg[4] = {0.f, 0.f, 0.f, 0.f};
#pragma unroll
  for (int rt = 0; rt < 4; ++rt) {
    f32x4 acc[4];
#pragma unroll
    for (int ct = 0; ct < 4; ++ct) acc[ct] = (f32x4){0.f, 0.f, 0.f, 0.f};
#pragma unroll
    for (int kt = 0; kt < 4; ++kt) {
      const bf16x8 a = *(const bf16x8*)(sH + (rt * 16 + lanelo) * HPAD + kt * 32 + quad * 8);
#pragma unroll
      for (int ct = 0; ct < 4; ++ct)
        acc[ct] = __builtin_amdgcn_mfma_f32_16x16x32_bf16(a, bw2[ct * 4 + kt], acc[ct], 0, 0, 0);
    }
#pragma unroll
    for (int reg = 0; reg < 4; ++reg) {
      const int j = rt * 16 + quad * 4 + reg;
      const float sc = sScale[j];
      const unsigned short* yr = (const unsigned short*)(sYB + j * SYPAD) + wbase + lanelo;
#pragma unroll
      for (int ct = 0; ct < 4; ++ct)
        pagg[ct] = fmaf(sc * (acc[ct][reg] + b2r[ct]), bf2f(yr[ct * 16]), pagg[ct]);
    }
  }

  __syncthreads();                 // sH/sYB reads done -> alias sH as sPart
  float* sPart = (float*)sH;
#pragma unroll
  for (int ct = 0; ct < 4; ++ct)
    sPart[quad * NF + wbase + ct * 16 + lanelo] = pagg[ct];
  __syncthreads();
  aggB[(size_t)ga * NF + t] =
      f2bf(sPart[t] + sPart[NF + t] + sPart[2 * NF + t] + sPart[3 * NF + t]);
}

// ---------------- per-layer update (fused W12, 2 GEMMs) ----------------
// v = aggB@W12T + b12 + vang; x += ssp(v); yB = bf16(x_new) @ in2fT
#define TPAD 136
__global__ __launch_bounds__(256) void k_upd(
    float* __restrict__ x, const short* __restrict__ aggB,
    const float* __restrict__ vang,
    const short* __restrict__ W12Tl, const float* __restrict__ b12l,
    const short* __restrict__ in2fT, short* __restrict__ yB) {
  __shared__ alignas(16) short sT[16 * TPAD];
  const int t = threadIdx.x;
  const int lane = t & 63, wave = t >> 6;
  const int lanelo = lane & 15, quad = lane >> 4;
  const int wbase = wave << 5;               // 4 waves x 32 cols
  const int row = (blockIdx.x << 4) + lanelo;

  // GEMM_A: v = aggB @ W12T
  f32x4 c2[2] = {{0.f, 0.f, 0.f, 0.f}, {0.f, 0.f, 0.f, 0.f}};
#pragma unroll
  for (int kt = 0; kt < 4; ++kt) {
    const bf16x8 b = *(const bf16x8*)(aggB + (size_t)row * 128 + kt * 32 + quad * 8);
#pragma unroll
    for (int ct = 0; ct < 2; ++ct) {
      const bf16x8 a = *(const bf16x8*)(W12Tl + (wbase + ct * 16 + lanelo) * 128 + kt * 32 + quad * 8);
      c2[ct] = __builtin_amdgcn_mfma_f32_16x16x32_bf16(a, b, c2[ct], 0, 0, 0);
    }
  }

  // epilogue: x += ssp(v + b12 + vang); stage x_new bf16
#pragma unroll
  for (int ct = 0; ct < 2; ++ct) {
    const int c0 = wbase + ct * 16 + quad * 4;
    const float4 dv = *(const float4*)(b12l + c0);
    const float4 vv = *(const float4*)(vang + (size_t)row * 128 + c0);
    float* xp = x + (size_t)row * 128 + c0;
    const float4 xv = *(const float4*)xp;
    float4 xo;
    xo.x = xv.x + sspf(c2[ct][0] + vv.x + dv.x);
    xo.y = xv.y + sspf(c2[ct][1] + vv.y + dv.y);
    xo.z = xv.z + sspf(c2[ct][2] + vv.z + dv.z);
    xo.w = xv.w + sspf(c2[ct][3] + vv.w + dv.w);
    *(float4*)xp = xo;
    if (in2fT != nullptr) {
      uint2 pk; pk.x = pk2bf(xo.x, xo.y); pk.y = pk2bf(xo.z, xo.w);
      *(uint2*)(sT + lanelo * TPAD + c0) = pk;
    }
  }
  if (in2fT == nullptr) return;
  __syncthreads();

  // GEMM_B: yB = x_new @ in2fT (bf16 out)
  f32x4 c3[2] = {{0.f, 0.f, 0.f, 0.f}, {0.f, 0.f, 0.f, 0.f}};
#pragma unroll
  for (int kt = 0; kt < 4; ++kt) {
    const bf16x8 b = *(const bf16x8*)(sT + lanelo * TPAD + kt * 32 + quad * 8);
#pragma unroll
    for (int ct = 0; ct < 2; ++ct) {
      const bf16x8 a = *(const bf16x8*)(in2fT + (wbase + ct * 16 + lanelo) * 128 + kt * 32 + quad * 8);
      c3[ct] = __builtin_amdgcn_mfma_f32_16x16x32_bf16(a, b, c3[ct], 0, 0, 0);
    }
  }
#pragma unroll
  for (int ct = 0; ct < 2; ++ct) {
    const int c0 = wbase + ct * 16 + quad * 4;
    uint2 pk; pk.x = pk2bf(c3[ct][0], c3[ct][1]); pk.y = pk2bf(c3[ct][2], c3[ct][3]);
    *(uint2*)(yB + (size_t)row * 128 + c0) = pk;
  }
}

extern "C" void kernel_launch(void* const* d_in, const int* in_sizes, int n_in,
                              void* d_out, int out_size, void* d_ws, size_t ws_size,
                              hipStream_t stream) {
  (void)in_sizes; (void)n_in; (void)out_size; (void)ws_size;
  const int* zn = (const int*)d_in[0];
  const float* pos = (const float*)d_in[1];
  const int* nbr = (const int*)d_in[2];
  const int* nmask = (const int*)d_in[3];
  const float* Gi = (const float*)d_in[4];
  const float* emb = (const float*)d_in[5];
  const float* fw1 = (const float*)d_in[6];
  const float* fb1 = (const float*)d_in[7];
  const float* fw2 = (const float*)d_in[8];
  const float* fb2 = (const float*)d_in[9];
  const float* in2f = (const float*)d_in[10];
  const float* f2o = (const float*)d_in[11];
  const float* f2ob = (const float*)d_in[12];
  const float* dwp = (const float*)d_in[13];
  const float* dbp = (const float*)d_in[14];
  const float* awp = (const float*)d_in[15];

  float* x = (float*)d_out;                            // [B,A,D] fp32
  float* vang = (float*)d_ws;                          // [3][B*A][128] fp32
  float* b12 = vang + (size_t)3 * NB * NA * ND;        // [3][128] fp32
  short* yB = (short*)(b12 + 3 * 128);                 // [B,A,F] bf16
  short* aggB = yB + (size_t)NB * NA * NF;             // [B,A,F] bf16
  short* w1T = aggB + (size_t)NB * NA * NF;            // [3][128][32]
  short* w2T = w1T + NW1;                              // [3][128][128]
  short* in2fT = w2T + NSQ;                            // [3][128][128]
  short* awT = in2fT + NSQ;                            // [3][128][512]
  short* W12T = awT + NAW;                             // [3][128][128]
  short* embYB = W12T + NSQ;                           // [112][128]

  k_prepw<<<(NW1 + 2 * NSQ + NAW) / 256, 256, 0, stream>>>(
      fw1, fw2, in2f, awp, w1T, w2T, in2fT, awT);
  k_prepfuse<<<dim3(8, 3), 256, 0, stream>>>(f2o, f2ob, dwp, dbp, W12T, b12);
  k_prepemb<<<7, 256, 0, stream>>>(emb, in2fT, embYB);
  k_init2<<<NB * NA / 2, 256, 0, stream>>>(zn, emb, embYB, x, yB);
  k_vang<<<dim3(NB * NA / 16, 3), 256, 0, stream>>>(Gi, awT, vang);
  for (int l = 0; l < 3; ++l) {
    k_cfconv<<<NB * NA, 128, 0, stream>>>(pos, nbr, nmask, yB,
        w1T + (size_t)l * 128 * 32, fb1 + (size_t)l * NF,
        w2T + (size_t)l * 128 * 128, fb2 + (size_t)l * NF, aggB);
    k_upd<<<NB * NA / 16, 256, 0, stream>>>(x, aggB,
        vang + (size_t)l * NB * NA * ND,
        W12T + (size_t)l * 16384, b12 + (size_t)l * 128,
        (l < 2) ? (in2fT + (size_t)(l + 1) * 16384) : nullptr, yB);
  }
}

// Round 7
// 268.987 us; speedup vs baseline: 1.1029x; 1.1029x over previous
//
#include <hip/hip_runtime.h>
#include <math.h>

#define NB 8
#define NA 512
#define NN 64
#define ND 128
#define NF 128
#define NG 25
#define NGA 512

typedef __attribute__((ext_vector_type(8))) short bf16x8;
typedef __attribute__((ext_vector_type(4))) float f32x4;

__device__ __forceinline__ float sspf(float v) {
  return fmaxf(v, 0.0f) + __logf(1.0f + __expf(-fabsf(v))) - 0.6931471805599453f;
}

__device__ __forceinline__ short f2bf(float x) {
  union { float f; unsigned u; } v; v.f = x;
  unsigned r = v.u + 0x7fffu + ((v.u >> 16) & 1u);   // RNE
  return (short)(r >> 16);
}

__device__ __forceinline__ unsigned pk2bf(float a, float b) {
  union { float f; unsigned u; } x, y; x.f = a; y.f = b;
  const unsigned ra = (x.u + 0x7fffu + ((x.u >> 16) & 1u)) >> 16;
  const unsigned rb = (y.u + 0x7fffu + ((y.u >> 16) & 1u)) & 0xffff0000u;
  return ra | rb;
}

__device__ __forceinline__ float bf2f(unsigned short us) {
  union { unsigned u; float f; } v; v.u = ((unsigned)us) << 16; return v.f;
}

__device__ __forceinline__ bf16x8 pack8(float4 a, float4 b) {
  bf16x8 r;
  r[0] = f2bf(a.x); r[1] = f2bf(a.y); r[2] = f2bf(a.z); r[3] = f2bf(a.w);
  r[4] = f2bf(b.x); r[5] = f2bf(b.y); r[6] = f2bf(b.z); r[7] = f2bf(b.w);
  return r;
}

// ---------------- prep: bf16 transposed weight copies ----------------
#define NW1 (3 * 128 * 32)       // 12288
#define NSQ (3 * 128 * 128)     // 49152
#define NAW (3 * 128 * 512)     // 196608
__global__ __launch_bounds__(256) void k_prepw(
    const float* __restrict__ fw1, const float* __restrict__ fw2,
    const float* __restrict__ in2f, const float* __restrict__ aw,
    short* __restrict__ w1T, short* __restrict__ w2T,
    short* __restrict__ in2fT, short* __restrict__ awT) {
  int idx = blockIdx.x * 256 + threadIdx.x;
  if (idx < NW1) {
    const int l = idx >> 12, r = idx & 4095, n = r >> 5, k = r & 31;
    w1T[idx] = (k < NG) ? f2bf(fw1[(size_t)l * NG * NF + k * NF + n]) : (short)0;
    return;
  }
  idx -= NW1;
  if (idx < 2 * NSQ) {
    const int which = idx / NSQ, q = idx % NSQ;
    const int l = q >> 14, r = q & 16383, n = r >> 7, k = r & 127;
    const float* src = (which == 0) ? fw2 : in2f;
    short* dst = (which == 0) ? w2T : in2fT;
    dst[q] = f2bf(src[(size_t)l * 16384 + k * 128 + n]);
    return;
  }
  idx -= 2 * NSQ;
  if (idx < NAW) {
    const int l = idx >> 16, r = idx & 65535, n = r >> 9, k = r & 511;
    awT[idx] = f2bf(aw[(size_t)l * 65536 + k * 128 + n]);
  }
}

// ---------------- fused weight: W12 = f2o@dw, b12 = f2ob@dw + db ----------------
__global__ __launch_bounds__(256) void k_prepfuse(
    const float* __restrict__ f2o, const float* __restrict__ f2ob,
    const float* __restrict__ dw, const float* __restrict__ db,
    short* __restrict__ W12T, float* __restrict__ b12) {
  const int t = threadIdx.x;
  const int lane = t & 63, wave = t >> 6;
  const int lanelo = lane & 15, quad = lane >> 4;
  const int wbase = wave << 5;
  const int l = blockIdx.y;
  const int i = (blockIdx.x << 4) + lanelo;
  const float* f2o_l = f2o + (size_t)l * 16384;
  const float* dw_l = dw + (size_t)l * 16384;
  short* W12T_l = W12T + (size_t)l * 16384;

  f32x4 c[2] = {{0.f, 0.f, 0.f, 0.f}, {0.f, 0.f, 0.f, 0.f}};
#pragma unroll
  for (int kt = 0; kt < 4; ++kt) {
    const int k0 = kt * 32 + quad * 8;
    const bf16x8 b = pack8(*(const float4*)(f2o_l + (size_t)i * 128 + k0),
                           *(const float4*)(f2o_l + (size_t)i * 128 + k0 + 4));
#pragma unroll
    for (int ct = 0; ct < 2; ++ct) {
      const int j = wbase + ct * 16 + lanelo;
      bf16x8 a;
#pragma unroll
      for (int idx = 0; idx < 8; ++idx)
        a[idx] = f2bf(dw_l[(size_t)(k0 + idx) * 128 + j]);
      c[ct] = __builtin_amdgcn_mfma_f32_16x16x32_bf16(a, b, c[ct], 0, 0, 0);
    }
  }
#pragma unroll
  for (int ct = 0; ct < 2; ++ct) {
#pragma unroll
    for (int reg = 0; reg < 4; ++reg) {
      const int j = wbase + ct * 16 + quad * 4 + reg;
      W12T_l[(size_t)j * 128 + i] = f2bf(c[ct][reg]);
    }
  }
  if (blockIdx.x == 0 && t < 128) {
    const int j = t;
    float acc = db[(size_t)l * 128 + j];
    for (int k = 0; k < 128; ++k)
      acc += f2ob[(size_t)l * 128 + k] * dw_l[(size_t)k * 128 + j];
    b12[(size_t)l * 128 + j] = acc;
  }
}

// ---------------- embY = emb @ in2f[0] -> bf16 [112][128] ----------------
__global__ __launch_bounds__(256) void k_prepemb(const float* __restrict__ emb,
                                                 const short* __restrict__ in2fT0,
                                                 short* __restrict__ embYB) {
  const int t = threadIdx.x;
  const int lane = t & 63, wave = t >> 6;
  const int lanelo = lane & 15, quad = lane >> 4;
  const int wbase = wave << 5;
  const int z = (blockIdx.x << 4) + lanelo;
  const int zc = (z < 100) ? z : 99;
  f32x4 c[2] = {{0.f, 0.f, 0.f, 0.f}, {0.f, 0.f, 0.f, 0.f}};
#pragma unroll
  for (int kt = 0; kt < 4; ++kt) {
    const int k0 = kt * 32 + quad * 8;
    const bf16x8 b = pack8(*(const float4*)(emb + (size_t)zc * 128 + k0),
                           *(const float4*)(emb + (size_t)zc * 128 + k0 + 4));
#pragma unroll
    for (int ct = 0; ct < 2; ++ct) {
      const bf16x8 a = *(const bf16x8*)(in2fT0 + (wbase + ct * 16 + lanelo) * 128 + k0);
      c[ct] = __builtin_amdgcn_mfma_f32_16x16x32_bf16(a, b, c[ct], 0, 0, 0);
    }
  }
  if (z < 100) {
#pragma unroll
    for (int ct = 0; ct < 2; ++ct) {
      const int c0 = wbase + ct * 16 + quad * 4;
      uint2 pk; pk.x = pk2bf(c[ct][0], c[ct][1]); pk.y = pk2bf(c[ct][2], c[ct][3]);
      *(uint2*)(embYB + (size_t)z * 128 + c0) = pk;
    }
  }
}

// ---------------- gather: x = emb[zn], yB = embYB[zn] ----------------
__global__ __launch_bounds__(256) void k_init2(const int* __restrict__ zn,
                                               const float* __restrict__ emb,
                                               const short* __restrict__ embYB,
                                               float* __restrict__ x,
                                               short* __restrict__ yB) {
  const int t = threadIdx.x;
  const int ga = blockIdx.x * 2 + (t >> 7);
  const int tt = t & 127;
  const int z = zn[ga];
  x[(size_t)ga * 128 + tt] = emb[(size_t)z * 128 + tt];
  yB[(size_t)ga * 128 + tt] = embYB[(size_t)z * 128 + tt];
}

// ---------------- hoisted angular GEMM: vang[l] = bf16(Gi) @ awT[l] ----------------
__global__ __launch_bounds__(256) void k_vang(const float* __restrict__ Gi,
                                              const short* __restrict__ awT,
                                              float* __restrict__ vang) {
  const int t = threadIdx.x;
  const int lane = t & 63, wave = t >> 6;
  const int lanelo = lane & 15, quad = lane >> 4;
  const int wbase = wave << 5;
  const int l = blockIdx.y;
  const int row = (blockIdx.x << 4) + lanelo;
  const short* aw = awT + (size_t)l * 128 * NGA;
  f32x4 c[2] = {{0.f, 0.f, 0.f, 0.f}, {0.f, 0.f, 0.f, 0.f}};
#pragma unroll
  for (int kt = 0; kt < 16; ++kt) {
    const int k0 = kt * 32 + quad * 8;
    const bf16x8 b = pack8(*(const float4*)(Gi + (size_t)row * NGA + k0),
                           *(const float4*)(Gi + (size_t)row * NGA + k0 + 4));
#pragma unroll
    for (int ct = 0; ct < 2; ++ct) {
      const bf16x8 a = *(const bf16x8*)(aw + (size_t)(wbase + ct * 16 + lanelo) * NGA + k0);
      c[ct] = __builtin_amdgcn_mfma_f32_16x16x32_bf16(a, b, c[ct], 0, 0, 0);
    }
  }
  float* vrow = vang + ((size_t)l * NB * NA + row) * 128;
#pragma unroll
  for (int ct = 0; ct < 2; ++ct) {
    float4 o = make_float4(c[ct][0], c[ct][1], c[ct][2], c[ct][3]);
    *(float4*)(vrow + wbase + ct * 16 + quad * 4) = o;
  }
}

// ---------------- fused CFConv: 4 waves per atom, slim LDS ----------------
// wave w owns f-cols [w*32, w*32+32); y read directly from global bf16 (L2-hot).
#define HPAD 136
__global__ __launch_bounds__(256) void k_cfconv(
    const float* __restrict__ pos, const int* __restrict__ nbr,
    const int* __restrict__ nmask, const short* __restrict__ yB,
    const short* __restrict__ w1T, const float* __restrict__ b1,
    const short* __restrict__ w2T, const float* __restrict__ b2,
    short* __restrict__ aggB) {
  __shared__ alignas(16) short sH[NN * HPAD];   // 17408 B; aliased as sPart at end
  __shared__ float sR[NN];
  __shared__ float sScale[NN];
  __shared__ int sNbr[NN];

  const int t = threadIdx.x;
  const int ga = blockIdx.x;
  const int b0 = ga & ~(NA - 1);
  const int lane = t & 63;
  const int wave = t >> 6;
  const int lanelo = lane & 15;
  const int quad = lane >> 4;
  const int wbase = wave << 5;     // 32 cols per wave

  // weight fragments (broadcast across blocks -> L2): 2 + 8 frags = 40 VGPRs
  bf16x8 bw1[2];
  bf16x8 bw2[8];
#pragma unroll
  for (int ct = 0; ct < 2; ++ct) {
    const int n = wbase + ct * 16 + lanelo;
    bw1[ct] = *(const bf16x8*)(w1T + n * 32 + quad * 8);
#pragma unroll
    for (int kt = 0; kt < 4; ++kt)
      bw2[ct * 4 + kt] = *(const bf16x8*)(w2T + n * 128 + kt * 32 + quad * 8);
  }
  float b1r[2], b2r[2];
#pragma unroll
  for (int ct = 0; ct < 2; ++ct) {
    b1r[ct] = b1[wbase + ct * 16 + lanelo];
    b2r[ct] = b2[wbase + ct * 16 + lanelo];
  }

  if (t < NN) {
    const int nj = nbr[(size_t)ga * NN + t];
    sNbr[t] = nj;
    const float px = pos[(size_t)ga * 3];
    const float py = pos[(size_t)ga * 3 + 1];
    const float pz = pos[(size_t)ga * 3 + 2];
    const float* pj = pos + (size_t)(b0 + nj) * 3;
    const float dx = pj[0] - px, dy = pj[1] - py, dz = pj[2] - pz;
    const float r = sqrtf(dx * dx + dy * dy + dz * dz + 1e-12f);
    sR[t] = r;
    sScale[t] = (r <= 5.0f && nmask[(size_t)ga * NN + t] != 0) ? 1.0f : 0.0f;
  }
  __syncthreads();

  const float step = 3.8f / 24.0f;
  const float coef = -0.5f / (step * step);

  // ---- phase 1: h = ssp(f @ w1 + b1) -> bf16 LDS ----
#pragma unroll
  for (int rt = 0; rt < 4; ++rt) {
    const float r = sR[rt * 16 + lanelo];
    bf16x8 a;
#pragma unroll
    for (int i = 0; i < 8; ++i) {
      const int g = quad * 8 + i;
      const float d = r - (1.2f + step * (float)g);
      const float e = __expf(coef * d * d);
      a[i] = (g < NG) ? f2bf(e) : (short)0;
    }
#pragma unroll
    for (int ct = 0; ct < 2; ++ct) {
      f32x4 c = {0.f, 0.f, 0.f, 0.f};
      c = __builtin_amdgcn_mfma_f32_16x16x32_bf16(a, bw1[ct], c, 0, 0, 0);
      const int f = wbase + ct * 16 + lanelo;
      const float b1f = b1r[ct];
#pragma unroll
      for (int reg = 0; reg < 4; ++reg) {
        const int j = rt * 16 + quad * 4 + reg;
        sH[j * HPAD + f] = f2bf(sspf(c[reg] + b1f));
      }
    }
  }
  __syncthreads();

  // ---- phase 2: W = h @ w2; consume against global bf16 y gathers ----
  float pagg[2] = {0.f, 0.f};
#pragma unroll
  for (int rt = 0; rt < 4; ++rt) {
    f32x4 acc[2];
    acc[0] = (f32x4){0.f, 0.f, 0.f, 0.f};
    acc[1] = (f32x4){0.f, 0.f, 0.f, 0.f};
#pragma unroll
    for (int kt = 0; kt < 4; ++kt) {
      const bf16x8 a = *(const bf16x8*)(sH + (rt * 16 + lanelo) * HPAD + kt * 32 + quad * 8);
#pragma unroll
      for (int ct = 0; ct < 2; ++ct)
        acc[ct] = __builtin_amdgcn_mfma_f32_16x16x32_bf16(a, bw2[ct * 4 + kt], acc[ct], 0, 0, 0);
    }
#pragma unroll
    for (int reg = 0; reg < 4; ++reg) {
      const int j = rt * 16 + quad * 4 + reg;
      const float sc = sScale[j];
      const unsigned short* yr =
          (const unsigned short*)(yB + (size_t)(b0 + sNbr[j]) * NF) + wbase + lanelo;
#pragma unroll
      for (int ct = 0; ct < 2; ++ct)
        pagg[ct] = fmaf(sc * (acc[ct][reg] + b2r[ct]), bf2f(yr[ct * 16]), pagg[ct]);
    }
  }

  __syncthreads();                 // sH reads done -> alias as sPart [4][128] fp32
  float* sPart = (float*)sH;
#pragma unroll
  for (int ct = 0; ct < 2; ++ct)
    sPart[quad * NF + wbase + ct * 16 + lanelo] = pagg[ct];
  __syncthreads();
  if (t < NF)
    aggB[(size_t)ga * NF + t] =
        f2bf(sPart[t] + sPart[NF + t] + sPart[2 * NF + t] + sPart[3 * NF + t]);
}

// ---------------- per-layer update (fused W12, 2 GEMMs) ----------------
#define TPAD 136
__global__ __launch_bounds__(256) void k_upd(
    float* __restrict__ x, const short* __restrict__ aggB,
    const float* __restrict__ vang,
    const short* __restrict__ W12Tl, const float* __restrict__ b12l,
    const short* __restrict__ in2fT, short* __restrict__ yB) {
  __shared__ alignas(16) short sT[16 * TPAD];
  const int t = threadIdx.x;
  const int lane = t & 63, wave = t >> 6;
  const int lanelo = lane & 15, quad = lane >> 4;
  const int wbase = wave << 5;               // 4 waves x 32 cols
  const int row = (blockIdx.x << 4) + lanelo;

  // GEMM_A: v = aggB @ W12T
  f32x4 c2[2] = {{0.f, 0.f, 0.f, 0.f}, {0.f, 0.f, 0.f, 0.f}};
#pragma unroll
  for (int kt = 0; kt < 4; ++kt) {
    const bf16x8 b = *(const bf16x8*)(aggB + (size_t)row * 128 + kt * 32 + quad * 8);
#pragma unroll
    for (int ct = 0; ct < 2; ++ct) {
      const bf16x8 a = *(const bf16x8*)(W12Tl + (wbase + ct * 16 + lanelo) * 128 + kt * 32 + quad * 8);
      c2[ct] = __builtin_amdgcn_mfma_f32_16x16x32_bf16(a, b, c2[ct], 0, 0, 0);
    }
  }

  // epilogue: x += ssp(v + b12 + vang); stage x_new bf16
#pragma unroll
  for (int ct = 0; ct < 2; ++ct) {
    const int c0 = wbase + ct * 16 + quad * 4;
    const float4 dv = *(const float4*)(b12l + c0);
    const float4 vv = *(const float4*)(vang + (size_t)row * 128 + c0);
    float* xp = x + (size_t)row * 128 + c0;
    const float4 xv = *(const float4*)xp;
    float4 xo;
    xo.x = xv.x + sspf(c2[ct][0] + vv.x + dv.x);
    xo.y = xv.y + sspf(c2[ct][1] + vv.y + dv.y);
    xo.z = xv.z + sspf(c2[ct][2] + vv.z + dv.z);
    xo.w = xv.w + sspf(c2[ct][3] + vv.w + dv.w);
    *(float4*)xp = xo;
    if (in2fT != nullptr) {
      uint2 pk; pk.x = pk2bf(xo.x, xo.y); pk.y = pk2bf(xo.z, xo.w);
      *(uint2*)(sT + lanelo * TPAD + c0) = pk;
    }
  }
  if (in2fT == nullptr) return;
  __syncthreads();

  // GEMM_B: yB = x_new @ in2fT (bf16 out)
  f32x4 c3[2] = {{0.f, 0.f, 0.f, 0.f}, {0.f, 0.f, 0.f, 0.f}};
#pragma unroll
  for (int kt = 0; kt < 4; ++kt) {
    const bf16x8 b = *(const bf16x8*)(sT + lanelo * TPAD + kt * 32 + quad * 8);
#pragma unroll
    for (int ct = 0; ct < 2; ++ct) {
      const bf16x8 a = *(const bf16x8*)(in2fT + (wbase + ct * 16 + lanelo) * 128 + kt * 32 + quad * 8);
      c3[ct] = __builtin_amdgcn_mfma_f32_16x16x32_bf16(a, b, c3[ct], 0, 0, 0);
    }
  }
#pragma unroll
  for (int ct = 0; ct < 2; ++ct) {
    const int c0 = wbase + ct * 16 + quad * 4;
    uint2 pk; pk.x = pk2bf(c3[ct][0], c3[ct][1]); pk.y = pk2bf(c3[ct][2], c3[ct][3]);
    *(uint2*)(yB + (size_t)row * 128 + c0) = pk;
  }
}

extern "C" void kernel_launch(void* const* d_in, const int* in_sizes, int n_in,
                              void* d_out, int out_size, void* d_ws, size_t ws_size,
                              hipStream_t stream) {
  (void)in_sizes; (void)n_in; (void)out_size; (void)ws_size;
  const int* zn = (const int*)d_in[0];
  const float* pos = (const float*)d_in[1];
  const int* nbr = (const int*)d_in[2];
  const int* nmask = (const int*)d_in[3];
  const float* Gi = (const float*)d_in[4];
  const float* emb = (const float*)d_in[5];
  const float* fw1 = (const float*)d_in[6];
  const float* fb1 = (const float*)d_in[7];
  const float* fw2 = (const float*)d_in[8];
  const float* fb2 = (const float*)d_in[9];
  const float* in2f = (const float*)d_in[10];
  const float* f2o = (const float*)d_in[11];
  const float* f2ob = (const float*)d_in[12];
  const float* dwp = (const float*)d_in[13];
  const float* dbp = (const float*)d_in[14];
  const float* awp = (const float*)d_in[15];

  float* x = (float*)d_out;                            // [B,A,D] fp32
  float* vang = (float*)d_ws;                          // [3][B*A][128] fp32
  float* b12 = vang + (size_t)3 * NB * NA * ND;        // [3][128] fp32
  short* yB = (short*)(b12 + 3 * 128);                 // [B,A,F] bf16
  short* aggB = yB + (size_t)NB * NA * NF;             // [B,A,F] bf16
  short* w1T = aggB + (size_t)NB * NA * NF;            // [3][128][32]
  short* w2T = w1T + NW1;                              // [3][128][128]
  short* in2fT = w2T + NSQ;                            // [3][128][128]
  short* awT = in2fT + NSQ;                            // [3][128][512]
  short* W12T = awT + NAW;                             // [3][128][128]
  short* embYB = W12T + NSQ;                           // [112][128]

  k_prepw<<<(NW1 + 2 * NSQ + NAW) / 256, 256, 0, stream>>>(
      fw1, fw2, in2f, awp, w1T, w2T, in2fT, awT);
  k_prepfuse<<<dim3(8, 3), 256, 0, stream>>>(f2o, f2ob, dwp, dbp, W12T, b12);
  k_prepemb<<<7, 256, 0, stream>>>(emb, in2fT, embYB);
  k_init2<<<NB * NA / 2, 256, 0, stream>>>(zn, emb, embYB, x, yB);
  k_vang<<<dim3(NB * NA / 16, 3), 256, 0, stream>>>(Gi, awT, vang);
  for (int l = 0; l < 3; ++l) {
    k_cfconv<<<NB * NA, 256, 0, stream>>>(pos, nbr, nmask, yB,
        w1T + (size_t)l * 128 * 32, fb1 + (size_t)l * NF,
        w2T + (size_t)l * 128 * 128, fb2 + (size_t)l * NF, aggB);
    k_upd<<<NB * NA / 16, 256, 0, stream>>>(x, aggB,
        vang + (size_t)l * NB * NA * ND,
        W12T + (size_t)l * 16384, b12 + (size_t)l * 128,
        (l < 2) ? (in2fT + (size_t)l * 16384 + 16384) : nullptr, yB);
  }
}

// Round 8
// 261.312 us; speedup vs baseline: 1.1353x; 1.0294x over previous
//
#include <hip/hip_runtime.h>
#include <math.h>

#define NB 8
#define NA 512
#define NN 64
#define ND 128
#define NF 128
#define NG 25
#define NGA 512

typedef __attribute__((ext_vector_type(8))) short bf16x8;
typedef __attribute__((ext_vector_type(4))) float f32x4;

__device__ __forceinline__ float sspf(float v) {
  return fmaxf(v, 0.0f) + __logf(1.0f + __expf(-fabsf(v))) - 0.6931471805599453f;
}

__device__ __forceinline__ short f2bf(float x) {
  union { float f; unsigned u; } v; v.f = x;
  unsigned r = v.u + 0x7fffu + ((v.u >> 16) & 1u);   // RNE
  return (short)(r >> 16);
}

__device__ __forceinline__ unsigned pk2bf(float a, float b) {
  union { float f; unsigned u; } x, y; x.f = a; y.f = b;
  const unsigned ra = (x.u + 0x7fffu + ((x.u >> 16) & 1u)) >> 16;
  const unsigned rb = (y.u + 0x7fffu + ((y.u >> 16) & 1u)) & 0xffff0000u;
  return ra | rb;
}

__device__ __forceinline__ float bf2f(unsigned short us) {
  union { unsigned u; float f; } v; v.u = ((unsigned)us) << 16; return v.f;
}

__device__ __forceinline__ bf16x8 pack8(float4 a, float4 b) {
  bf16x8 r;
  r[0] = f2bf(a.x); r[1] = f2bf(a.y); r[2] = f2bf(a.z); r[3] = f2bf(a.w);
  r[4] = f2bf(b.x); r[5] = f2bf(b.y); r[6] = f2bf(b.z); r[7] = f2bf(b.w);
  return r;
}

// ---------------- prep: bf16 transposed weight copies ----------------
#define NW1 (3 * 128 * 32)       // 12288
#define NSQ (3 * 128 * 128)     // 49152
#define NAW (3 * 128 * 512)     // 196608
__global__ __launch_bounds__(256) void k_prepw(
    const float* __restrict__ fw1, const float* __restrict__ fw2,
    const float* __restrict__ in2f, const float* __restrict__ aw,
    short* __restrict__ w1T, short* __restrict__ w2T,
    short* __restrict__ in2fT, short* __restrict__ awT) {
  int idx = blockIdx.x * 256 + threadIdx.x;
  if (idx < NW1) {
    const int l = idx >> 12, r = idx & 4095, n = r >> 5, k = r & 31;
    w1T[idx] = (k < NG) ? f2bf(fw1[(size_t)l * NG * NF + k * NF + n]) : (short)0;
    return;
  }
  idx -= NW1;
  if (idx < 2 * NSQ) {
    const int which = idx / NSQ, q = idx % NSQ;
    const int l = q >> 14, r = q & 16383, n = r >> 7, k = r & 127;
    const float* src = (which == 0) ? fw2 : in2f;
    short* dst = (which == 0) ? w2T : in2fT;
    dst[q] = f2bf(src[(size_t)l * 16384 + k * 128 + n]);
    return;
  }
  idx -= 2 * NSQ;
  if (idx < NAW) {
    const int l = idx >> 16, r = idx & 65535, n = r >> 9, k = r & 511;
    awT[idx] = f2bf(aw[(size_t)l * 65536 + k * 128 + n]);
  }
}

// ---------------- fused weight: W12 = f2o@dw, b12 = f2ob@dw + db ----------------
__global__ __launch_bounds__(256) void k_prepfuse(
    const float* __restrict__ f2o, const float* __restrict__ f2ob,
    const float* __restrict__ dw, const float* __restrict__ db,
    short* __restrict__ W12T, float* __restrict__ b12) {
  const int t = threadIdx.x;
  const int lane = t & 63, wave = t >> 6;
  const int lanelo = lane & 15, quad = lane >> 4;
  const int wbase = wave << 5;
  const int l = blockIdx.y;
  const int i = (blockIdx.x << 4) + lanelo;
  const float* f2o_l = f2o + (size_t)l * 16384;
  const float* dw_l = dw + (size_t)l * 16384;
  short* W12T_l = W12T + (size_t)l * 16384;

  f32x4 c[2] = {{0.f, 0.f, 0.f, 0.f}, {0.f, 0.f, 0.f, 0.f}};
#pragma unroll
  for (int kt = 0; kt < 4; ++kt) {
    const int k0 = kt * 32 + quad * 8;
    const bf16x8 b = pack8(*(const float4*)(f2o_l + (size_t)i * 128 + k0),
                           *(const float4*)(f2o_l + (size_t)i * 128 + k0 + 4));
#pragma unroll
    for (int ct = 0; ct < 2; ++ct) {
      const int j = wbase + ct * 16 + lanelo;
      bf16x8 a;
#pragma unroll
      for (int idx = 0; idx < 8; ++idx)
        a[idx] = f2bf(dw_l[(size_t)(k0 + idx) * 128 + j]);
      c[ct] = __builtin_amdgcn_mfma_f32_16x16x32_bf16(a, b, c[ct], 0, 0, 0);
    }
  }
#pragma unroll
  for (int ct = 0; ct < 2; ++ct) {
#pragma unroll
    for (int reg = 0; reg < 4; ++reg) {
      const int j = wbase + ct * 16 + quad * 4 + reg;
      W12T_l[(size_t)j * 128 + i] = f2bf(c[ct][reg]);
    }
  }
  if (blockIdx.x == 0 && t < 128) {
    const int j = t;
    float acc = db[(size_t)l * 128 + j];
    for (int k = 0; k < 128; ++k)
      acc += f2ob[(size_t)l * 128 + k] * dw_l[(size_t)k * 128 + j];
    b12[(size_t)l * 128 + j] = acc;
  }
}

// ---------------- embY = emb @ in2f[0] -> bf16 [112][128] ----------------
__global__ __launch_bounds__(256) void k_prepemb(const float* __restrict__ emb,
                                                 const short* __restrict__ in2fT0,
                                                 short* __restrict__ embYB) {
  const int t = threadIdx.x;
  const int lane = t & 63, wave = t >> 6;
  const int lanelo = lane & 15, quad = lane >> 4;
  const int wbase = wave << 5;
  const int z = (blockIdx.x << 4) + lanelo;
  const int zc = (z < 100) ? z : 99;
  f32x4 c[2] = {{0.f, 0.f, 0.f, 0.f}, {0.f, 0.f, 0.f, 0.f}};
#pragma unroll
  for (int kt = 0; kt < 4; ++kt) {
    const int k0 = kt * 32 + quad * 8;
    const bf16x8 b = pack8(*(const float4*)(emb + (size_t)zc * 128 + k0),
                           *(const float4*)(emb + (size_t)zc * 128 + k0 + 4));
#pragma unroll
    for (int ct = 0; ct < 2; ++ct) {
      const bf16x8 a = *(const bf16x8*)(in2fT0 + (wbase + ct * 16 + lanelo) * 128 + k0);
      c[ct] = __builtin_amdgcn_mfma_f32_16x16x32_bf16(a, b, c[ct], 0, 0, 0);
    }
  }
  if (z < 100) {
#pragma unroll
    for (int ct = 0; ct < 2; ++ct) {
      const int c0 = wbase + ct * 16 + quad * 4;
      uint2 pk; pk.x = pk2bf(c[ct][0], c[ct][1]); pk.y = pk2bf(c[ct][2], c[ct][3]);
      *(uint2*)(embYB + (size_t)z * 128 + c0) = pk;
    }
  }
}

// ---------------- gather: x = emb[zn], yB = embYB[zn] ----------------
__global__ __launch_bounds__(256) void k_init2(const int* __restrict__ zn,
                                               const float* __restrict__ emb,
                                               const short* __restrict__ embYB,
                                               float* __restrict__ x,
                                               short* __restrict__ yB) {
  const int t = threadIdx.x;
  const int ga = blockIdx.x * 2 + (t >> 7);
  const int tt = t & 127;
  const int z = zn[ga];
  x[(size_t)ga * 128 + tt] = emb[(size_t)z * 128 + tt];
  yB[(size_t)ga * 128 + tt] = embYB[(size_t)z * 128 + tt];
}

// ---------------- hoisted angular GEMM: vang[l] = bf16(Gi) @ awT[l] ----------------
__global__ __launch_bounds__(256) void k_vang(const float* __restrict__ Gi,
                                              const short* __restrict__ awT,
                                              float* __restrict__ vang) {
  const int t = threadIdx.x;
  const int lane = t & 63, wave = t >> 6;
  const int lanelo = lane & 15, quad = lane >> 4;
  const int wbase = wave << 5;
  const int l = blockIdx.y;
  const int row = (blockIdx.x << 4) + lanelo;
  const short* aw = awT + (size_t)l * 128 * NGA;
  f32x4 c[2] = {{0.f, 0.f, 0.f, 0.f}, {0.f, 0.f, 0.f, 0.f}};
#pragma unroll
  for (int kt = 0; kt < 16; ++kt) {
    const int k0 = kt * 32 + quad * 8;
    const bf16x8 b = pack8(*(const float4*)(Gi + (size_t)row * NGA + k0),
                           *(const float4*)(Gi + (size_t)row * NGA + k0 + 4));
#pragma unroll
    for (int ct = 0; ct < 2; ++ct) {
      const bf16x8 a = *(const bf16x8*)(aw + (size_t)(wbase + ct * 16 + lanelo) * NGA + k0);
      c[ct] = __builtin_amdgcn_mfma_f32_16x16x32_bf16(a, b, c[ct], 0, 0, 0);
    }
  }
  float* vrow = vang + ((size_t)l * NB * NA + row) * 128;
#pragma unroll
  for (int ct = 0; ct < 2; ++ct) {
    float4 o = make_float4(c[ct][0], c[ct][1], c[ct][2], c[ct][3]);
    *(float4*)(vrow + wbase + ct * 16 + quad * 4) = o;
  }
}

// ---------------- fused CFConv: 4 waves/atom, deduped gaussians, swapped phase1 ----
#define HPAD 136
__global__ __launch_bounds__(256) void k_cfconv(
    const float* __restrict__ pos, const int* __restrict__ nbr,
    const int* __restrict__ nmask, const short* __restrict__ yB,
    const short* __restrict__ w1T, const float* __restrict__ b1,
    const short* __restrict__ w2T, const float* __restrict__ b2,
    short* __restrict__ aggB) {
  __shared__ alignas(16) short sH[NN * HPAD];   // 17408 B; aliased as sPart at end
  __shared__ alignas(16) short sF[NN * 32];     // gaussian f-matrix [j][g], 4 KB
  __shared__ float sR[NN];
  __shared__ float sScale[NN];
  __shared__ int sNbr[NN];

  const int t = threadIdx.x;
  const int ga = blockIdx.x;
  const int b0 = ga & ~(NA - 1);
  const int lane = t & 63;
  const int wave = t >> 6;
  const int lanelo = lane & 15;
  const int quad = lane >> 4;
  const int wbase = wave << 5;     // 32 f-cols per wave

  // weight fragments (broadcast across blocks -> L2)
  bf16x8 bw1[2];
  bf16x8 bw2[8];
#pragma unroll
  for (int ct = 0; ct < 2; ++ct) {
    const int n = wbase + ct * 16 + lanelo;
    bw1[ct] = *(const bf16x8*)(w1T + n * 32 + quad * 8);
#pragma unroll
    for (int kt = 0; kt < 4; ++kt)
      bw2[ct * 4 + kt] = *(const bf16x8*)(w2T + n * 128 + kt * 32 + quad * 8);
  }
  // phase-1 bias: 4 consecutive f per lane per ct (C-init)
  float4 b1v[2];
  // phase-2 bias: one f per lane per ct (C-init, same across 4 j-regs)
  float b2r[2];
#pragma unroll
  for (int ct = 0; ct < 2; ++ct) {
    b1v[ct] = *(const float4*)(b1 + wbase + ct * 16 + quad * 4);
    b2r[ct] = b2[wbase + ct * 16 + lanelo];
  }

  if (t < NN) {
    const int nj = nbr[(size_t)ga * NN + t];
    sNbr[t] = nj;
    const float px = pos[(size_t)ga * 3];
    const float py = pos[(size_t)ga * 3 + 1];
    const float pz = pos[(size_t)ga * 3 + 2];
    const float* pj = pos + (size_t)(b0 + nj) * 3;
    const float dx = pj[0] - px, dy = pj[1] - py, dz = pj[2] - pz;
    const float r = sqrtf(dx * dx + dy * dy + dz * dz + 1e-12f);
    sR[t] = r;
    sScale[t] = (r <= 5.0f && nmask[(size_t)ga * NN + t] != 0) ? 1.0f : 0.0f;
  }
  __syncthreads();

  // ---- build gaussian matrix cooperatively: thread -> j=wave*16+lanelo, g=quad*8.. ----
  {
    const float step = 3.8f / 24.0f;
    const float coef = -0.5f / (step * step);
    const float r = sR[wave * 16 + lanelo];
    bf16x8 gf;
#pragma unroll
    for (int i = 0; i < 8; ++i) {
      const int g = quad * 8 + i;
      const float d = r - (1.2f + step * (float)g);
      gf[i] = (g < NG) ? f2bf(__expf(coef * d * d)) : (short)0;
    }
    *(bf16x8*)(sF + (wave * 16 + lanelo) * 32 + quad * 8) = gf;
  }
  __syncthreads();

  // ---- phase 1 (swapped): C[f][j] = w1^T x f^T; lane: j=lanelo, f=f0+reg ----
#pragma unroll
  for (int jt = 0; jt < 4; ++jt) {
    const int j = jt * 16 + lanelo;
    const bf16x8 gb = *(const bf16x8*)(sF + j * 32 + quad * 8);
#pragma unroll
    for (int ct = 0; ct < 2; ++ct) {
      f32x4 c = {b1v[ct].x, b1v[ct].y, b1v[ct].z, b1v[ct].w};
      c = __builtin_amdgcn_mfma_f32_16x16x32_bf16(bw1[ct], gb, c, 0, 0, 0);
      const int f0 = wbase + ct * 16 + quad * 4;
      uint2 pk;
      pk.x = pk2bf(sspf(c[0]), sspf(c[1]));
      pk.y = pk2bf(sspf(c[2]), sspf(c[3]));
      *(uint2*)(sH + j * HPAD + f0) = pk;
    }
  }
  __syncthreads();

  // ---- phase 2: W = h @ w2 (+b2 via C-init); consume against global bf16 y ----
  float pagg[2] = {0.f, 0.f};
#pragma unroll
  for (int rt = 0; rt < 4; ++rt) {
    f32x4 acc[2];
    acc[0] = (f32x4){b2r[0], b2r[0], b2r[0], b2r[0]};
    acc[1] = (f32x4){b2r[1], b2r[1], b2r[1], b2r[1]};
#pragma unroll
    for (int kt = 0; kt < 4; ++kt) {
      const bf16x8 a = *(const bf16x8*)(sH + (rt * 16 + lanelo) * HPAD + kt * 32 + quad * 8);
#pragma unroll
      for (int ct = 0; ct < 2; ++ct)
        acc[ct] = __builtin_amdgcn_mfma_f32_16x16x32_bf16(a, bw2[ct * 4 + kt], acc[ct], 0, 0, 0);
    }
#pragma unroll
    for (int reg = 0; reg < 4; ++reg) {
      const int j = rt * 16 + quad * 4 + reg;
      const float sc = sScale[j];
      const unsigned short* yr =
          (const unsigned short*)(yB + (size_t)(b0 + sNbr[j]) * NF) + wbase + lanelo;
#pragma unroll
      for (int ct = 0; ct < 2; ++ct)
        pagg[ct] = fmaf(sc * acc[ct][reg], bf2f(yr[ct * 16]), pagg[ct]);
    }
  }

  __syncthreads();                 // sH reads done -> alias as sPart [4][128] fp32
  float* sPart = (float*)sH;
#pragma unroll
  for (int ct = 0; ct < 2; ++ct)
    sPart[quad * NF + wbase + ct * 16 + lanelo] = pagg[ct];
  __syncthreads();
  if (t < NF)
    aggB[(size_t)ga * NF + t] =
        f2bf(sPart[t] + sPart[NF + t] + sPart[2 * NF + t] + sPart[3 * NF + t]);
}

// ---------------- per-layer update (fused W12, 2 GEMMs) ----------------
#define TPAD 136
__global__ __launch_bounds__(256) void k_upd(
    float* __restrict__ x, const short* __restrict__ aggB,
    const float* __restrict__ vang,
    const short* __restrict__ W12Tl, const float* __restrict__ b12l,
    const short* __restrict__ in2fT, short* __restrict__ yB) {
  __shared__ alignas(16) short sT[16 * TPAD];
  const int t = threadIdx.x;
  const int lane = t & 63, wave = t >> 6;
  const int lanelo = lane & 15, quad = lane >> 4;
  const int wbase = wave << 5;               // 4 waves x 32 cols
  const int row = (blockIdx.x << 4) + lanelo;

  // GEMM_A: v = aggB @ W12T
  f32x4 c2[2] = {{0.f, 0.f, 0.f, 0.f}, {0.f, 0.f, 0.f, 0.f}};
#pragma unroll
  for (int kt = 0; kt < 4; ++kt) {
    const bf16x8 b = *(const bf16x8*)(aggB + (size_t)row * 128 + kt * 32 + quad * 8);
#pragma unroll
    for (int ct = 0; ct < 2; ++ct) {
      const bf16x8 a = *(const bf16x8*)(W12Tl + (wbase + ct * 16 + lanelo) * 128 + kt * 32 + quad * 8);
      c2[ct] = __builtin_amdgcn_mfma_f32_16x16x32_bf16(a, b, c2[ct], 0, 0, 0);
    }
  }

  // epilogue: x += ssp(v + b12 + vang); stage x_new bf16
#pragma unroll
  for (int ct = 0; ct < 2; ++ct) {
    const int c0 = wbase + ct * 16 + quad * 4;
    const float4 dv = *(const float4*)(b12l + c0);
    const float4 vv = *(const float4*)(vang + (size_t)row * 128 + c0);
    float* xp = x + (size_t)row * 128 + c0;
    const float4 xv = *(const float4*)xp;
    float4 xo;
    xo.x = xv.x + sspf(c2[ct][0] + vv.x + dv.x);
    xo.y = xv.y + sspf(c2[ct][1] + vv.y + dv.y);
    xo.z = xv.z + sspf(c2[ct][2] + vv.z + dv.z);
    xo.w = xv.w + sspf(c2[ct][3] + vv.w + dv.w);
    *(float4*)xp = xo;
    if (in2fT != nullptr) {
      uint2 pk; pk.x = pk2bf(xo.x, xo.y); pk.y = pk2bf(xo.z, xo.w);
      *(uint2*)(sT + lanelo * TPAD + c0) = pk;
    }
  }
  if (in2fT == nullptr) return;
  __syncthreads();

  // GEMM_B: yB = x_new @ in2fT (bf16 out)
  f32x4 c3[2] = {{0.f, 0.f, 0.f, 0.f}, {0.f, 0.f, 0.f, 0.f}};
#pragma unroll
  for (int kt = 0; kt < 4; ++kt) {
    const bf16x8 b = *(const bf16x8*)(sT + lanelo * TPAD + kt * 32 + quad * 8);
#pragma unroll
    for (int ct = 0; ct < 2; ++ct) {
      const bf16x8 a = *(const bf16x8*)(in2fT + (wbase + ct * 16 + lanelo) * 128 + kt * 32 + quad * 8);
      c3[ct] = __builtin_amdgcn_mfma_f32_16x16x32_bf16(a, b, c3[ct], 0, 0, 0);
    }
  }
#pragma unroll
  for (int ct = 0; ct < 2; ++ct) {
    const int c0 = wbase + ct * 16 + quad * 4;
    uint2 pk; pk.x = pk2bf(c3[ct][0], c3[ct][1]); pk.y = pk2bf(c3[ct][2], c3[ct][3]);
    *(uint2*)(yB + (size_t)row * 128 + c0) = pk;
  }
}

extern "C" void kernel_launch(void* const* d_in, const int* in_sizes, int n_in,
                              void* d_out, int out_size, void* d_ws, size_t ws_size,
                              hipStream_t stream) {
  (void)in_sizes; (void)n_in; (void)out_size; (void)ws_size;
  const int* zn = (const int*)d_in[0];
  const float* pos = (const float*)d_in[1];
  const int* nbr = (const int*)d_in[2];
  const int* nmask = (const int*)d_in[3];
  const float* Gi = (const float*)d_in[4];
  const float* emb = (const float*)d_in[5];
  const float* fw1 = (const float*)d_in[6];
  const float* fb1 = (const float*)d_in[7];
  const float* fw2 = (const float*)d_in[8];
  const float* fb2 = (const float*)d_in[9];
  const float* in2f = (const float*)d_in[10];
  const float* f2o = (const float*)d_in[11];
  const float* f2ob = (const float*)d_in[12];
  const float* dwp = (const float*)d_in[13];
  const float* dbp = (const float*)d_in[14];
  const float* awp = (const float*)d_in[15];

  float* x = (float*)d_out;                            // [B,A,D] fp32
  float* vang = (float*)d_ws;                          // [3][B*A][128] fp32
  float* b12 = vang + (size_t)3 * NB * NA * ND;        // [3][128] fp32
  short* yB = (short*)(b12 + 3 * 128);                 // [B,A,F] bf16
  short* aggB = yB + (size_t)NB * NA * NF;             // [B,A,F] bf16
  short* w1T = aggB + (size_t)NB * NA * NF;            // [3][128][32]
  short* w2T = w1T + NW1;                              // [3][128][128]
  short* in2fT = w2T + NSQ;                            // [3][128][128]
  short* awT = in2fT + NSQ;                            // [3][128][512]
  short* W12T = awT + NAW;                             // [3][128][128]
  short* embYB = W12T + NSQ;                           // [112][128]

  k_prepw<<<(NW1 + 2 * NSQ + NAW) / 256, 256, 0, stream>>>(
      fw1, fw2, in2f, awp, w1T, w2T, in2fT, awT);
  k_prepfuse<<<dim3(8, 3), 256, 0, stream>>>(f2o, f2ob, dwp, dbp, W12T, b12);
  k_prepemb<<<7, 256, 0, stream>>>(emb, in2fT, embYB);
  k_init2<<<NB * NA / 2, 256, 0, stream>>>(zn, emb, embYB, x, yB);
  k_vang<<<dim3(NB * NA / 16, 3), 256, 0, stream>>>(Gi, awT, vang);
  for (int l = 0; l < 3; ++l) {
    k_cfconv<<<NB * NA, 256, 0, stream>>>(pos, nbr, nmask, yB,
        w1T + (size_t)l * 128 * 32, fb1 + (size_t)l * NF,
        w2T + (size_t)l * 128 * 128, fb2 + (size_t)l * NF, aggB);
    k_upd<<<NB * NA / 16, 256, 0, stream>>>(x, aggB,
        vang + (size_t)l * NB * NA * ND,
        W12T + (size_t)l * 16384, b12 + (size_t)l * 128,
        (l < 2) ? (in2fT + (size_t)l * 16384 + 16384) : nullptr, yB);
  }
}